// Round 22
// baseline (180.568 us; speedup 1.0000x reference)
//
#include <hip/hip_runtime.h>

typedef unsigned short u16;
typedef unsigned int u32;
typedef __attribute__((ext_vector_type(8))) short short8;
typedef __attribute__((ext_vector_type(8))) unsigned short u16x8;
typedef __attribute__((ext_vector_type(4))) float f32x4;

#define T_TOK 4096
#define DIM   1024
#define NEXP  16
#define INTER 512
#define NSH   1024
#define CAP   4096
#define BM  128
#define BN1 64
#define BN2 128
#define BK  64
#define N1MAX 1152       // 512 shared + 640 routed worst case
#define N2MAX 112        // 32 shared + 80 routed worst case
#define NTR2 2304        // w2 (2048) + s2 (256) tr64 tiles, hosted in k_route

__device__ __forceinline__ u16 f2bf(float f) {
  union { float f; u32 u; } c; c.f = f;
  u32 u = c.u;
  return (u16)((u + 0x7FFFu + ((u >> 16) & 1u)) >> 16);
}
__device__ __forceinline__ float bf2f(u16 b) {
  union { u32 u; float f; } c; c.u = ((u32)b) << 16;
  return c.f;
}

typedef __attribute__((address_space(1))) u32 u32_g;
typedef __attribute__((address_space(3))) u32 u32_l;
__device__ __forceinline__ void gload16(const u16* g, u16* l) {
  __builtin_amdgcn_global_load_lds((u32_g*)g, (u32_l*)l, 16, 0, 0);
}

// 64x64 transpose-convert tile; 256 threads; float4 loads, u16x8 (16B) stores.
__device__ __forceinline__ void tr64(float (*tile)[65],
                                     const float* __restrict__ src, u16* __restrict__ dst,
                                     int R, int C, int r0, int c0, int tid) {
  const int c4 = (tid & 15) * 4;
  const int rr = tid >> 4;                 // 0..15
#pragma unroll
  for (int i = 0; i < 4; ++i) {
    float4 v = *reinterpret_cast<const float4*>(&src[(size_t)(r0 + rr + 16 * i) * C + c0 + c4]);
    tile[rr + 16 * i][c4]     = v.x;
    tile[rr + 16 * i][c4 + 1] = v.y;
    tile[rr + 16 * i][c4 + 2] = v.z;
    tile[rr + 16 * i][c4 + 3] = v.w;
  }
  __syncthreads();
  const int cg  = (tid & 7) * 8;
  const int orw = tid >> 3;                // 0..31
#pragma unroll
  for (int i = 0; i < 2; ++i) {
    const int c = orw + 32 * i;            // output row (= source column)
    u16x8 o;
#pragma unroll
    for (int j = 0; j < 8; ++j) o[j] = f2bf(tile[cg + j][c]);
    *reinterpret_cast<u16x8*>(&dst[(size_t)(c0 + c) * R + r0 + cg]) = o;
  }
  __syncthreads();
}

// ---------------- k_gwt: gw [E][D] -> gwT4 [D/4][E] float4 blocks (64KB) ----------------
__global__ void __launch_bounds__(256) k_gwt(const float* __restrict__ gw,
                                             float4* __restrict__ gwT4) {
  const int g = blockIdx.x * 256 + threadIdx.x;   // 0..4095 = e*256 + d4
  const int e = g >> 8, d4 = g & 255;
  float4 v = *reinterpret_cast<const float4*>(&gw[(size_t)e * DIM + 4 * d4]);
  gwT4[d4 * NEXP + e] = v;
}

// ---------------- k_prep: cvt(x) + fp64 scores (coalesced gwT4) + tr64 of w1,w3,s1,s3 ----------------
// phase-interleaved (R21); ids: [0,2048) score | [2048,6144) cvt | [6144,8192) w1
// | [8192,10240) w3 | [10240,10496) s1 | [10496,10752) s3
__global__ void __launch_bounds__(256) k_prep(const float* __restrict__ x,
                                              const float4* __restrict__ gwT4,
                                              u16* __restrict__ xb,
                                              double* __restrict__ scores,
                                              const float* __restrict__ We1, u16* __restrict__ w1t,
                                              const float* __restrict__ We3, u16* __restrict__ w3t,
                                              const float* __restrict__ ws1, u16* __restrict__ s1t,
                                              const float* __restrict__ ws3, u16* __restrict__ s3t,
                                              int* __restrict__ counts) {
  const int id = (blockIdx.x % 42) * 256 + (blockIdx.x / 42);   // bijective interleave
  const int tid = threadIdx.x;
  __shared__ double red[256];
  __shared__ __align__(16) float tile[64][65];

  if (id < 2048) {
    if (id == 0 && tid < 32) counts[tid] = 0;   // counts[0..15], ticket[16], nums[17..18]
    const int e   = tid & 15;
    const int tk  = (tid >> 4) & 1;
    const int seg = tid >> 5;
    const int t   = id * 2 + tk;
    const float* xr = x + (size_t)t * DIM + seg * 128;
    const float4* wr = gwT4 + (size_t)seg * 32 * NEXP + e;   // [seg*32 + i][e]
    double a0 = 0.0, a1 = 0.0;
#pragma unroll 8
    for (int i = 0; i < 32; ++i) {
      float4 xv = *reinterpret_cast<const float4*>(xr + i * 4);
      float4 wv = wr[i * NEXP];
      double s = (double)xv.x * (double)wv.x + (double)xv.y * (double)wv.y
               + (double)xv.z * (double)wv.z + (double)xv.w * (double)wv.w;
      if (i & 1) a1 += s; else a0 += s;
    }
    red[tid] = a0 + a1;
    __syncthreads();
    if (tid < 32) {
      double s = red[tid];
#pragma unroll
      for (int q = 1; q < 8; ++q) s += red[tid + 32 * q];
      scores[(size_t)(id * 2 + (tid >> 4)) * NEXP + (tid & 15)] = s;
    }
    return;
  }
  if (id < 6144) {
    const int i = ((id - 2048) * 256 + tid) * 4;
    float4 v = *reinterpret_cast<const float4*>(x + i);
    ushort4 o;
    o.x = f2bf(v.x); o.y = f2bf(v.y); o.z = f2bf(v.z); o.w = f2bf(v.w);
    *reinterpret_cast<ushort4*>(xb + i) = o;
    return;
  }
  const float* src; u16* dst; int R, C, rel;
  if (id < 8192)       { rel = id - 6144;  int e = rel >> 7; rel &= 127; src = We1 + (size_t)e * DIM * INTER; dst = w1t + (size_t)e * INTER * DIM; R = DIM; C = INTER; }
  else if (id < 10240) { rel = id - 8192;  int e = rel >> 7; rel &= 127; src = We3 + (size_t)e * DIM * INTER; dst = w3t + (size_t)e * INTER * DIM; R = DIM; C = INTER; }
  else if (id < 10496) { rel = id - 10240; src = ws1; dst = s1t; R = DIM; C = NSH; }
  else                 { rel = id - 10496; src = ws3; dst = s3t; R = DIM; C = NSH; }
  const int rx = C >> 6;
  const int r0 = (rel / rx) << 6;
  const int c0 = (rel % rx) << 6;
  tr64(tile, src, dst, R, C, r0, c0, tid);
}

// ---------------- k_route: blocks 0..15 routing + tables; blocks >=16 tr64 of w2/s2 ----------------
__global__ void __launch_bounds__(256) k_route(const double* __restrict__ scores,
                                               const float* __restrict__ gb,
                                               int* __restrict__ counts,
                                               int* __restrict__ bucket,
                                               float* __restrict__ tokw,
                                               u32* __restrict__ t1,
                                               u32* __restrict__ t2,
                                               const float* __restrict__ We2, u16* __restrict__ w2t,
                                               const float* __restrict__ ws2, u16* __restrict__ s2t) {
  if (blockIdx.x >= 16) {
    __shared__ __align__(16) float tile[64][65];
    const int ti = blockIdx.x - 16;        // 0..2303
    const float* src; u16* dst; int R, C, rel;
    if (ti < 2048) { rel = ti; int e2 = rel >> 7; rel &= 127; src = We2 + (size_t)e2 * INTER * DIM; dst = w2t + (size_t)e2 * DIM * INTER; R = INTER; C = DIM; }
    else           { rel = ti - 2048; src = ws2; dst = s2t; R = NSH; C = DIM; }
    const int rx = C >> 6;
    const int r0 = (rel / rx) << 6;
    const int c0 = (rel % rx) << 6;
    tr64(tile, src, dst, R, C, r0, c0, threadIdx.x);
    return;
  }
  const int t = blockIdx.x * 256 + threadIdx.x;
  {
    double s[NEXP];
#pragma unroll
    for (int e = 0; e < NEXP; ++e) s[e] = scores[(size_t)t * NEXP + e];
    double m = s[0];
#pragma unroll
    for (int e = 1; e < NEXP; ++e) m = s[e] > m ? s[e] : m;
    double ex[NEXP], sum = 0.0;
#pragma unroll
    for (int e = 0; e < NEXP; ++e) { ex[e] = exp(s[e] - m); sum += ex[e]; }
    double orig[NEXP], sc[NEXP];
#pragma unroll
    for (int e = 0; e < NEXP; ++e) { orig[e] = ex[e] / sum; sc[e] = orig[e] + (double)gb[e]; }
    double gs[4];
#pragma unroll
    for (int g = 0; g < 4; ++g) {
      double m1 = -1e300, m2 = -1e300;
#pragma unroll
      for (int j = 0; j < 4; ++j) {
        double v = sc[g * 4 + j];
        if (v > m1) { m2 = m1; m1 = v; } else if (v > m2) m2 = v;
      }
      gs[g] = m1 + m2;
    }
    int g1 = 0;
    for (int g = 1; g < 4; ++g) if (gs[g] > gs[g1]) g1 = g;
    int g2 = -1;
    for (int g = 0; g < 4; ++g) { if (g == g1) continue; if (g2 < 0 || gs[g] > gs[g2]) g2 = g; }
    int e1 = -1, e2 = -1;
    for (int e = 0; e < NEXP; ++e) {
      int g = e >> 2;
      if (g != g1 && g != g2) continue;
      if (e1 < 0 || sc[e] > sc[e1]) e1 = e;
    }
    for (int e = 0; e < NEXP; ++e) {
      int g = e >> 2;
      if ((g != g1 && g != g2) || e == e1) continue;
      if (e2 < 0 || sc[e] > sc[e2]) e2 = e;
    }
    tokw[2 * t]     = (float)orig[e1];
    tokw[2 * t + 1] = (float)orig[e2];
    int p0 = atomicAdd(&counts[e1], 1); bucket[e1 * CAP + p0] = 2 * t;
    int p1 = atomicAdd(&counts[e2], 1); bucket[e2 * CAP + p1] = 2 * t + 1;
  }
  // ---- last-to-finish routing block builds the tile work tables ----
  __shared__ int lastf;
  __shared__ int b1s[17], mtz[17];
  __syncthreads();
  if (threadIdx.x == 0) {
    __threadfence();
    lastf = (atomicAdd(&counts[16], 1) == 15) ? 1 : 0;
  }
  __syncthreads();
  if (!lastf) return;
  if (threadIdx.x == 0) {
    int n1 = 0, n2 = 0;
    for (int z = 0; z < 17; ++z) {
      int m = (z == 0) ? (T_TOK / BM) : ((atomicAdd(&counts[z - 1], 0) + BM - 1) >> 7);
      int ntz = (z == 0) ? (NSH / BN1) : (INTER / BN1);
      b1s[z] = n1; mtz[z] = m;
      n1 += m * ntz; n2 += m;
    }
    counts[17] = n1; counts[18] = n2;
  }
  __syncthreads();
  int off2 = 0;
  for (int z = 0; z < 17; ++z) {
    const int ntz = (z == 0) ? (NSH / BN1) : (INTER / BN1);
    const int m = mtz[z];
    for (int i = threadIdx.x; i < m * ntz; i += 256)
      t1[b1s[z] + i] = ((u32)z << 16) | ((u32)(i / ntz) << 8) | (u32)(i % ntz);
    for (int i = threadIdx.x; i < m; i += 256)
      t2[off2 + i] = ((u32)z << 8) | (u32)i;
    off2 += m;
  }
}

// ---------------- k_g1: table-driven SwiGLU GEMM; REGISTER DIET + lb(256,4) ----------------
// Unified-file budget: 64 acc (AGPR) + arch VGPRs <= 128 total for 4 waves/SIMD.
// Diet: row-index ints instead of pointer arrays; B addressed base + p*32*DIM consts.
__global__ void __launch_bounds__(256, 4) k_g1(
    const u16* __restrict__ A, const u16* __restrict__ w1t, const u16* __restrict__ w3t,
    const u16* __restrict__ s1t, const u16* __restrict__ s3t,
    const float* __restrict__ be1, const float* __restrict__ be3,
    const float* __restrict__ bs1, const float* __restrict__ bs3,
    u16* __restrict__ hr, u16* __restrict__ hs,
    const int* __restrict__ counts, const int* __restrict__ bucket,
    const u32* __restrict__ t1) {
  const int tid = threadIdx.x;
  __shared__ __align__(16) u16 lA[BM * BK];
  __shared__ __align__(16) u16 lB1[BN1 * BK];
  __shared__ __align__(16) u16 lB3[BN1 * BK];

  int idx = blockIdx.x;
  const int n1 = counts[17];
  if (idx >= n1) return;
  // XCD-chunked bijective swizzle (m204)
  {
    const int xq = idx & 7, k = idx >> 3;
    const int q = n1 >> 3, r = n1 & 7;
    idx = (xq < r ? xq * (q + 1) : r * (q + 1) + (xq - r) * q) + k;
  }
  const u32 en = t1[idx];
  const int z = en >> 16, mt = (en >> 8) & 255, nt = en & 255;
  const bool sh = (z == 0);
  const int e = z - 1;
  const int M = sh ? T_TOK : counts[e];
  const int lane = tid & 63, wid = tid >> 6;

  const int srow = tid >> 3, sc16 = tid & 7;
  const int scsw = (sc16 ^ (srow & 7)) * 8;
  const int* bkt = bucket + e * CAP;

  // register diet: keep 4 row indices (ints), single A base; B as base + const strides
  int arow[4];
#pragma unroll
  for (int p = 0; p < 4; ++p) {
    int r = mt * BM + srow + p * 32;
    if (sh) arow[p] = r;
    else { int pos = r < M ? r : M - 1; arow[p] = bkt[pos] >> 1; }
  }
  const u16* Abase = A + scsw;
  const u16* b1b = (sh ? s1t : w1t + (size_t)e * INTER * DIM)
                 + (size_t)(nt * BN1 + srow) * DIM + scsw;
  const u16* b3b = (sh ? s3t : w3t + (size_t)e * INTER * DIM)
                 + (size_t)(nt * BN1 + srow) * DIM + scsw;

  f32x4 acc1[4][2], acc3[4][2];
#pragma unroll
  for (int i = 0; i < 4; ++i)
#pragma unroll
    for (int j = 0; j < 2; ++j) {
      acc1[i][j] = f32x4{0.f, 0.f, 0.f, 0.f};
      acc3[i][j] = f32x4{0.f, 0.f, 0.f, 0.f};
    }

  const int wm = wid >> 1, wn = wid & 1;
  const int fr = lane & 15, fs = lane >> 4;
  const int csA = fr & 7;

  for (int kt = 0; kt < DIM; kt += BK) {
#pragma unroll
    for (int p = 0; p < 4; ++p)
      gload16(Abase + (size_t)arow[p] * DIM + kt, &lA[(srow + 32 * p) * BK + sc16 * 8]);
#pragma unroll
    for (int p = 0; p < 2; ++p) {
      int ldso = (srow + 32 * p) * BK + sc16 * 8;
      gload16(b1b + (size_t)(p * 32) * DIM + kt, &lB1[ldso]);
      gload16(b3b + (size_t)(p * 32) * DIM + kt, &lB3[ldso]);
    }
    __syncthreads();
#pragma unroll
    for (int kk = 0; kk < 2; ++kk) {
      const int c = ((kk * 4 + fs) ^ csA) * 8;
      short8 af[4];
#pragma unroll
      for (int mi = 0; mi < 4; ++mi)
        af[mi] = *reinterpret_cast<const short8*>(&lA[(wm * 64 + mi * 16 + fr) * BK + c]);
#pragma unroll
      for (int ni = 0; ni < 2; ++ni) {
        short8 b1f = *reinterpret_cast<const short8*>(&lB1[(wn * 32 + ni * 16 + fr) * BK + c]);
        short8 b3f = *reinterpret_cast<const short8*>(&lB3[(wn * 32 + ni * 16 + fr) * BK + c]);
#pragma unroll
        for (int mi = 0; mi < 4; ++mi) {
          acc1[mi][ni] = __builtin_amdgcn_mfma_f32_16x16x32_bf16(af[mi], b1f, acc1[mi][ni], 0, 0, 0);
          acc3[mi][ni] = __builtin_amdgcn_mfma_f32_16x16x32_bf16(af[mi], b3f, acc3[mi][ni], 0, 0, 0);
        }
      }
    }
    __syncthreads();
  }

  const float* bp1 = sh ? bs1 : be1 + (size_t)e * INTER;
  const float* bp3 = sh ? bs3 : be3 + (size_t)e * INTER;
#pragma unroll
  for (int mi = 0; mi < 4; ++mi) {
#pragma unroll
    for (int j = 0; j < 4; ++j) {
      int p = mt * BM + wm * 64 + mi * 16 + fs * 4 + j;
      if (p >= M) continue;
      u16* hp = sh ? hs + (size_t)p * NSH : hr + (size_t)bkt[p] * INTER;
#pragma unroll
      for (int ni = 0; ni < 2; ++ni) {
        int gcol = nt * BN1 + wn * 32 + ni * 16 + fr;
        float v1 = acc1[mi][ni][j] + bp1[gcol];
        float v3 = acc3[mi][ni][j] + bp3[gcol];
        float hv = (v1 / (1.0f + __expf(-v1))) * v3;
        hp[gcol] = f2bf(hv);
      }
    }
  }
}

// ---------------- k_g2: table-driven, flat-XCD-swizzled; REGISTER DIET + lb(256,4) ----------------
__global__ void __launch_bounds__(256, 4) k_g2(
    const u16* __restrict__ hr, const u16* __restrict__ hs,
    const u16* __restrict__ w2t, const u16* __restrict__ s2t,
    const float* __restrict__ be2, const float* __restrict__ bs2,
    u16* __restrict__ yb, float* __restrict__ out,
    const int* __restrict__ counts, const int* __restrict__ bucket,
    const u32* __restrict__ t2) {
  // flat bijective XCD swizzle over 8*N2MAX = 896 blocks (divisible by 8)
  int lin = (int)(blockIdx.y * 8 + blockIdx.x);
  {
    const int xq = lin & 7, k = lin >> 3;
    lin = xq * (8 * N2MAX / 8) + k;       // chunk size = 112
  }
  const int by = lin >> 3, nt = lin & 7;
  if (by >= counts[18]) return;
  const u32 en = t2[by];
  const int z = en >> 8, mt = en & 255;
  const bool sh = (z == 0);
  const int e = z - 1;
  const int K = sh ? NSH : INTER;
  const int M = sh ? T_TOK : counts[e];
  const int tid = threadIdx.x;
  const int lane = tid & 63, wid = tid >> 6;

  __shared__ __align__(16) u16 lA[BM * BK];
  __shared__ __align__(16) u16 lB[BN2 * BK];

  const int srow = tid >> 3, sc16 = tid & 7;
  const int scsw = (sc16 ^ (srow & 7)) * 8;
  const int* bkt = bucket + e * CAP;

  int arow[4];
#pragma unroll
  for (int p = 0; p < 4; ++p) {
    int r = mt * BM + srow + p * 32;
    if (sh) arow[p] = r;
    else { int pos = r < M ? r : M - 1; arow[p] = bkt[pos]; }
  }
  const u16* Abase = (sh ? hs : hr) + scsw;
  const u16* Bb = (sh ? s2t : w2t + (size_t)e * DIM * INTER)
                + (size_t)(nt * BN2 + srow) * K + scsw;

  f32x4 acc[4][4];
#pragma unroll
  for (int i = 0; i < 4; ++i)
#pragma unroll
    for (int j = 0; j < 4; ++j) acc[i][j] = f32x4{0.f, 0.f, 0.f, 0.f};

  const int wm = wid >> 1, wn = wid & 1;
  const int fr = lane & 15, fs = lane >> 4;
  const int csA = fr & 7;

  for (int kt = 0; kt < K; kt += BK) {
#pragma unroll
    for (int p = 0; p < 4; ++p) {
      int ldso = (srow + 32 * p) * BK + sc16 * 8;
      gload16(Abase + (size_t)arow[p] * K + kt, &lA[ldso]);
      gload16(Bb + (size_t)(p * 32) * K + kt, &lB[ldso]);
    }
    __syncthreads();
#pragma unroll
    for (int kk = 0; kk < 2; ++kk) {
      const int c = ((kk * 4 + fs) ^ csA) * 8;
      short8 af[4];
#pragma unroll
      for (int mi = 0; mi < 4; ++mi)
        af[mi] = *reinterpret_cast<const short8*>(&lA[(wm * 64 + mi * 16 + fr) * BK + c]);
#pragma unroll
      for (int ni = 0; ni < 4; ++ni) {
        short8 bf = *reinterpret_cast<const short8*>(&lB[(wn * 64 + ni * 16 + fr) * BK + c]);
#pragma unroll
        for (int mi = 0; mi < 4; ++mi)
          acc[mi][ni] = __builtin_amdgcn_mfma_f32_16x16x32_bf16(af[mi], bf, acc[mi][ni], 0, 0, 0);
      }
    }
    __syncthreads();
  }

  const float* bp = sh ? bs2 : be2 + (size_t)e * DIM;
#pragma unroll
  for (int mi = 0; mi < 4; ++mi) {
#pragma unroll
    for (int j = 0; j < 4; ++j) {
      int p = mt * BM + wm * 64 + mi * 16 + fs * 4 + j;
      if (p >= M) continue;
#pragma unroll
      for (int ni = 0; ni < 4; ++ni) {
        int gcol = nt * BN2 + wn * 64 + ni * 16 + fr;
        float v = acc[mi][ni][j] + bp[gcol];
        if (sh) out[(size_t)p * DIM + gcol] = v;
        else    yb[(size_t)bkt[p] * DIM + gcol] = f2bf(v);
      }
    }
  }
}

// ---------------- final combine: out += w0*y[2t] + w1*y[2t+1] (y in bf16) ----------------
__global__ void __launch_bounds__(256) k_comb(float* __restrict__ out,
                                              const u16* __restrict__ yb,
                                              const float* __restrict__ tokw) {
  const int i = blockIdx.x * 256 + threadIdx.x;   // float4 index over [T][256]
  const int t = i >> 8, c4 = i & 255;
  const float w0 = tokw[2 * t], w1 = tokw[2 * t + 1];
  const ushort4 p = *reinterpret_cast<const ushort4*>(yb + ((size_t)(2 * t) << 10) + 4 * c4);
  const ushort4 q = *reinterpret_cast<const ushort4*>(yb + ((size_t)(2 * t + 1) << 10) + 4 * c4);
  float4* o = (float4*)out + ((size_t)t << 8);
  float4 a = o[c4];
  a.x += w0 * bf2f(p.x) + w1 * bf2f(q.x);
  a.y += w0 * bf2f(p.y) + w1 * bf2f(q.y);
  a.z += w0 * bf2f(p.z) + w1 * bf2f(q.z);
  a.w += w0 * bf2f(p.w) + w1 * bf2f(q.w);
  o[c4] = a;
}

extern "C" void kernel_launch(void* const* d_in, const int* in_sizes, int n_in,
                              void* d_out, int out_size, void* d_ws, size_t ws_size,
                              hipStream_t stream) {
  const float* x   = (const float*)d_in[0];
  const float* gw  = (const float*)d_in[1];
  const float* gb  = (const float*)d_in[2];
  const float* We1 = (const float*)d_in[3];
  const float* be1 = (const float*)d_in[4];
  const float* We2 = (const float*)d_in[5];
  const float* be2 = (const float*)d_in[6];
  const float* We3 = (const float*)d_in[7];
  const float* be3 = (const float*)d_in[8];
  const float* ws1 = (const float*)d_in[9];
  const float* bs1 = (const float*)d_in[10];
  const float* ws2 = (const float*)d_in[11];
  const float* bs2 = (const float*)d_in[12];
  const float* ws3 = (const float*)d_in[13];
  const float* bs3 = (const float*)d_in[14];
  float* out = (float*)d_out;

  // workspace carve (~68 MB); ybuf (bf16, 16.8 MB) aliases w1t (dead after k_g1)
  char* w = (char*)d_ws;
  int*    counts = (int*)w;    w += 256;              // [0..15] counts, [16] ticket, [17] n1, [18] n2
  u32*    t1     = (u32*)w;    w += N1MAX * 4;
  u32*    t2     = (u32*)w;    w += 512;              // N2MAX*4 = 448, rounded up
  float4* gwt4   = (float4*)w; w += (size_t)256 * NEXP * 16;   // 64KB
  int*    bucket = (int*)w;    w += (size_t)NEXP * CAP * 4;
  float*  tokw   = (float*)w;  w += (size_t)2 * T_TOK * 4;
  double* scor   = (double*)w; w += (size_t)T_TOK * NEXP * 8;
  u16*    xb     = (u16*)w;    w += (size_t)T_TOK * DIM * 2;
  char*   alias0 = w;
  u16*    w1t    = (u16*)w;    w += (size_t)NEXP * INTER * DIM * 2;
  u16*    w3t    = (u16*)w;    w += (size_t)NEXP * INTER * DIM * 2;
  u16*    w2t    = (u16*)w;    w += (size_t)NEXP * DIM * INTER * 2;
  u16*    s1t    = (u16*)w;    w += (size_t)NSH * DIM * 2;
  u16*    s3t    = (u16*)w;    w += (size_t)NSH * DIM * 2;
  u16*    s2t    = (u16*)w;    w += (size_t)DIM * NSH * 2;
  u16*    hr     = (u16*)w;    w += (size_t)2 * T_TOK * INTER * 2;
  u16*    hs     = (u16*)w;    w += (size_t)T_TOK * NSH * 2;
  u16*    ybuf   = (u16*)alias0;   // [2T][DIM] bf16 = 16.8MB, fits in w1t's slot

  // 0: gw -> gwT4 (64KB, makes score loads lane-contiguous)
  k_gwt<<<16, 256, 0, stream>>>(gw, gwt4);
  // 1: fused prep (phase-interleaved: cvt + scores + tr64 of g1-weights)
  k_prep<<<10752, 256, 0, stream>>>(x, gwt4, xb, scor, We1, w1t, We3, w3t,
                                    ws1, s1t, ws3, s3t, counts);
  // 2: route (16 blocks) + tr64 of We2/ws2 in the otherwise-idle window (2304 blocks)
  k_route<<<16 + NTR2, 256, 0, stream>>>(scor, gb, counts, bucket, tokw, t1, t2,
                                         We2, w2t, ws2, s2t);
  // 3: GEMM1 — register-diet, 4 blocks/CU
  k_g1<<<N1MAX, 256, 0, stream>>>(
      xb, w1t, w3t, s1t, s3t, be1, be3, bs1, bs3, hr, hs, counts, bucket, t1);
  // 4: GEMM2 — register-diet, 4 blocks/CU
  k_g2<<<dim3(8, N2MAX), 256, 0, stream>>>(
      hr, hs, w2t, s2t, be2, bs2, ybuf, out, counts, bucket, t2);
  // 5: combine
  k_comb<<<(T_TOK * DIM / 4) / 256, 256, 0, stream>>>(out, ybuf, tokw);
}

// Round 24
// 175.878 us; speedup vs baseline: 1.0267x; 1.0267x over previous
//
#include <hip/hip_runtime.h>

typedef unsigned short u16;
typedef unsigned int u32;
typedef __attribute__((ext_vector_type(8))) short short8;
typedef __attribute__((ext_vector_type(8))) unsigned short u16x8;
typedef __attribute__((ext_vector_type(4))) float f32x4;

#define T_TOK 4096
#define DIM   1024
#define NEXP  16
#define INTER 512
#define NSH   1024
#define CAP   4096
#define BM  128
#define BN1 64
#define BN2 128
#define BK  64
#define N1MAX 1152       // 512 shared + 640 routed worst case
#define N2MAX 112        // 32 shared + 80 routed worst case
#define NTR2 2304        // w2 (2048) + s2 (256) tr64 tiles, hosted in k_route

__device__ __forceinline__ u16 f2bf(float f) {
  union { float f; u32 u; } c; c.f = f;
  u32 u = c.u;
  return (u16)((u + 0x7FFFu + ((u >> 16) & 1u)) >> 16);
}
__device__ __forceinline__ float bf2f(u16 b) {
  union { u32 u; float f; } c; c.u = ((u32)b) << 16;
  return c.f;
}

typedef __attribute__((address_space(1))) u32 u32_g;
typedef __attribute__((address_space(3))) u32 u32_l;
__device__ __forceinline__ void gload16(const u16* g, u16* l) {
  __builtin_amdgcn_global_load_lds((u32_g*)g, (u32_l*)l, 16, 0, 0);
}

// 64x64 transpose-convert tile; 256 threads; float4 loads, u16x8 (16B) stores.
__device__ __forceinline__ void tr64(float (*tile)[65],
                                     const float* __restrict__ src, u16* __restrict__ dst,
                                     int R, int C, int r0, int c0, int tid) {
  const int c4 = (tid & 15) * 4;
  const int rr = tid >> 4;                 // 0..15
#pragma unroll
  for (int i = 0; i < 4; ++i) {
    float4 v = *reinterpret_cast<const float4*>(&src[(size_t)(r0 + rr + 16 * i) * C + c0 + c4]);
    tile[rr + 16 * i][c4]     = v.x;
    tile[rr + 16 * i][c4 + 1] = v.y;
    tile[rr + 16 * i][c4 + 2] = v.z;
    tile[rr + 16 * i][c4 + 3] = v.w;
  }
  __syncthreads();
  const int cg  = (tid & 7) * 8;
  const int orw = tid >> 3;                // 0..31
#pragma unroll
  for (int i = 0; i < 2; ++i) {
    const int c = orw + 32 * i;            // output row (= source column)
    u16x8 o;
#pragma unroll
    for (int j = 0; j < 8; ++j) o[j] = f2bf(tile[cg + j][c]);
    *reinterpret_cast<u16x8*>(&dst[(size_t)(c0 + c) * R + r0 + cg]) = o;
  }
  __syncthreads();
}

// ---------------- k_gwt: gw [E][D] -> gwT4 [D/4][E] float4 blocks (64KB) ----------------
__global__ void __launch_bounds__(256) k_gwt(const float* __restrict__ gw,
                                             float4* __restrict__ gwT4) {
  const int g = blockIdx.x * 256 + threadIdx.x;   // 0..4095 = e*256 + d4
  const int e = g >> 8, d4 = g & 255;
  float4 v = *reinterpret_cast<const float4*>(&gw[(size_t)e * DIM + 4 * d4]);
  gwT4[d4 * NEXP + e] = v;
}

// ---------------- k_prep: cvt(x) + fp64 scores (coalesced gwT4) + tr64 of w1,w3,s1,s3 ----------------
// PHASE-INTERLEAVED: p = (bid%42)*256 + bid/42 (10752 = 42*256) so every 42
// consecutive blocks sweep all phases; latency-bound score chains hide under
// the BW-bound cvt/tr streaming.
// phase ids: [0,2048) score | [2048,6144) cvt | [6144,8192) w1 | [8192,10240) w3
//            [10240,10496) s1 | [10496,10752) s3
__global__ void __launch_bounds__(256) k_prep(const float* __restrict__ x,
                                              const float4* __restrict__ gwT4,
                                              u16* __restrict__ xb,
                                              double* __restrict__ scores,
                                              const float* __restrict__ We1, u16* __restrict__ w1t,
                                              const float* __restrict__ We3, u16* __restrict__ w3t,
                                              const float* __restrict__ ws1, u16* __restrict__ s1t,
                                              const float* __restrict__ ws3, u16* __restrict__ s3t,
                                              int* __restrict__ counts) {
  const int id = (blockIdx.x % 42) * 256 + (blockIdx.x / 42);   // bijective interleave
  const int tid = threadIdx.x;
  __shared__ double red[256];
  __shared__ __align__(16) float tile[64][65];

  if (id < 2048) {
    if (id == 0 && tid < 32) counts[tid] = 0;   // counts[0..15], spare[16], n1[17], n2[18]
    const int e   = tid & 15;
    const int tk  = (tid >> 4) & 1;
    const int seg = tid >> 5;
    const int t   = id * 2 + tk;
    const float* xr = x + (size_t)t * DIM + seg * 128;
    const float4* wr = gwT4 + (size_t)seg * 32 * NEXP + e;   // [seg*32 + i][e]
    double a0 = 0.0, a1 = 0.0;
#pragma unroll 8
    for (int i = 0; i < 32; ++i) {
      float4 xv = *reinterpret_cast<const float4*>(xr + i * 4);
      float4 wv = wr[i * NEXP];
      double s = (double)xv.x * (double)wv.x + (double)xv.y * (double)wv.y
               + (double)xv.z * (double)wv.z + (double)xv.w * (double)wv.w;
      if (i & 1) a1 += s; else a0 += s;
    }
    red[tid] = a0 + a1;
    __syncthreads();
    if (tid < 32) {
      double s = red[tid];
#pragma unroll
      for (int q = 1; q < 8; ++q) s += red[tid + 32 * q];
      scores[(size_t)(id * 2 + (tid >> 4)) * NEXP + (tid & 15)] = s;
    }
    return;
  }
  if (id < 6144) {
    const int i = ((id - 2048) * 256 + tid) * 4;
    float4 v = *reinterpret_cast<const float4*>(x + i);
    ushort4 o;
    o.x = f2bf(v.x); o.y = f2bf(v.y); o.z = f2bf(v.z); o.w = f2bf(v.w);
    *reinterpret_cast<ushort4*>(xb + i) = o;
    return;
  }
  const float* src; u16* dst; int R, C, rel;
  if (id < 8192)       { rel = id - 6144;  int e = rel >> 7; rel &= 127; src = We1 + (size_t)e * DIM * INTER; dst = w1t + (size_t)e * INTER * DIM; R = DIM; C = INTER; }
  else if (id < 10240) { rel = id - 8192;  int e = rel >> 7; rel &= 127; src = We3 + (size_t)e * DIM * INTER; dst = w3t + (size_t)e * INTER * DIM; R = DIM; C = INTER; }
  else if (id < 10496) { rel = id - 10240; src = ws1; dst = s1t; R = DIM; C = NSH; }
  else                 { rel = id - 10496; src = ws3; dst = s3t; R = DIM; C = NSH; }
  const int rx = C >> 6;
  const int r0 = (rel / rx) << 6;
  const int c0 = (rel % rx) << 6;
  tr64(tile, src, dst, R, C, r0, c0, tid);
}

// ---------------- k_route: blocks 0..15 routing ONLY; blocks >=16 tr64 of w2/s2 ----------------
// Table building moved to k_plan (dedicated kernel) to eliminate the intra-kernel
// ticket pattern -- the only cross-block communication in the pipeline, and the
// prime suspect for the intermittent post-timing divergence seen in R23.
__global__ void __launch_bounds__(256) k_route(const double* __restrict__ scores,
                                               const float* __restrict__ gb,
                                               int* __restrict__ counts,
                                               int* __restrict__ bucket,
                                               float* __restrict__ tokw,
                                               const float* __restrict__ We2, u16* __restrict__ w2t,
                                               const float* __restrict__ ws2, u16* __restrict__ s2t) {
  if (blockIdx.x >= 16) {
    __shared__ __align__(16) float tile[64][65];
    const int ti = blockIdx.x - 16;        // 0..2303
    const float* src; u16* dst; int R, C, rel;
    if (ti < 2048) { rel = ti; int e2 = rel >> 7; rel &= 127; src = We2 + (size_t)e2 * INTER * DIM; dst = w2t + (size_t)e2 * DIM * INTER; R = INTER; C = DIM; }
    else           { rel = ti - 2048; src = ws2; dst = s2t; R = NSH; C = DIM; }
    const int rx = C >> 6;
    const int r0 = (rel / rx) << 6;
    const int c0 = (rel % rx) << 6;
    tr64(tile, src, dst, R, C, r0, c0, threadIdx.x);
    return;
  }
  const int t = blockIdx.x * 256 + threadIdx.x;
  double s[NEXP];
#pragma unroll
  for (int e = 0; e < NEXP; ++e) s[e] = scores[(size_t)t * NEXP + e];
  double m = s[0];
#pragma unroll
  for (int e = 1; e < NEXP; ++e) m = s[e] > m ? s[e] : m;
  double ex[NEXP], sum = 0.0;
#pragma unroll
  for (int e = 0; e < NEXP; ++e) { ex[e] = exp(s[e] - m); sum += ex[e]; }
  double orig[NEXP], sc[NEXP];
#pragma unroll
  for (int e = 0; e < NEXP; ++e) { orig[e] = ex[e] / sum; sc[e] = orig[e] + (double)gb[e]; }
  double gs[4];
#pragma unroll
  for (int g = 0; g < 4; ++g) {
    double m1 = -1e300, m2 = -1e300;
#pragma unroll
    for (int j = 0; j < 4; ++j) {
      double v = sc[g * 4 + j];
      if (v > m1) { m2 = m1; m1 = v; } else if (v > m2) m2 = v;
    }
    gs[g] = m1 + m2;
  }
  int g1 = 0;
  for (int g = 1; g < 4; ++g) if (gs[g] > gs[g1]) g1 = g;
  int g2 = -1;
  for (int g = 0; g < 4; ++g) { if (g == g1) continue; if (g2 < 0 || gs[g] > gs[g2]) g2 = g; }
  int e1 = -1, e2 = -1;
  for (int e = 0; e < NEXP; ++e) {
    int g = e >> 2;
    if (g != g1 && g != g2) continue;
    if (e1 < 0 || sc[e] > sc[e1]) e1 = e;
  }
  for (int e = 0; e < NEXP; ++e) {
    int g = e >> 2;
    if ((g != g1 && g != g2) || e == e1) continue;
    if (e2 < 0 || sc[e] > sc[e2]) e2 = e;
  }
  tokw[2 * t]     = (float)orig[e1];
  tokw[2 * t + 1] = (float)orig[e2];
  int p0 = atomicAdd(&counts[e1], 1); bucket[e1 * CAP + p0] = 2 * t;
  int p1 = atomicAdd(&counts[e2], 1); bucket[e2 * CAP + p1] = 2 * t + 1;
}

// ---------------- k_plan: single block; builds tile work tables from final counts ----------------
// Launched after k_route: counts are final and visible across the kernel boundary.
__global__ void __launch_bounds__(256) k_plan(int* __restrict__ counts,
                                              u32* __restrict__ t1,
                                              u32* __restrict__ t2) {
  __shared__ int b1s[17], mtz[17];
  const int tid = threadIdx.x;
  if (tid == 0) {
    int n1 = 0, n2 = 0;
    for (int z = 0; z < 17; ++z) {
      int m = (z == 0) ? (T_TOK / BM) : ((counts[z - 1] + BM - 1) >> 7);
      int ntz = (z == 0) ? (NSH / BN1) : (INTER / BN1);
      b1s[z] = n1; mtz[z] = m;
      n1 += m * ntz; n2 += m;
    }
    counts[17] = n1; counts[18] = n2;
  }
  __syncthreads();
  int off2 = 0;
  for (int z = 0; z < 17; ++z) {
    const int ntz = (z == 0) ? (NSH / BN1) : (INTER / BN1);
    const int m = mtz[z];
    for (int i = tid; i < m * ntz; i += 256)
      t1[b1s[z] + i] = ((u32)z << 16) | ((u32)(i / ntz) << 8) | (u32)(i % ntz);
    for (int i = tid; i < m; i += 256)
      t2[off2 + i] = ((u32)z << 8) | (u32)i;
    off2 += m;
  }
}

// ---------------- k_g1: PURE table-driven SwiGLU GEMM (sequential K, XCD-swizzled) ----------------
// BM=128 BN1=64 BK=64; wave tile 64 rows x 32 cols per matrix (4x2 acc x2)
__global__ void __launch_bounds__(256, 2) k_g1(
    const u16* __restrict__ A, const u16* __restrict__ w1t, const u16* __restrict__ w3t,
    const u16* __restrict__ s1t, const u16* __restrict__ s3t,
    const float* __restrict__ be1, const float* __restrict__ be3,
    const float* __restrict__ bs1, const float* __restrict__ bs3,
    u16* __restrict__ hr, u16* __restrict__ hs,
    const int* __restrict__ counts, const int* __restrict__ bucket,
    const u32* __restrict__ t1) {
  const int tid = threadIdx.x;
  __shared__ __align__(16) u16 lA[BM * BK];
  __shared__ __align__(16) u16 lB1[BN1 * BK];
  __shared__ __align__(16) u16 lB3[BN1 * BK];

  int idx = blockIdx.x;
  const int n1 = counts[17];
  if (idx >= n1) return;
  // XCD-chunked bijective swizzle (m204)
  {
    const int xq = idx & 7, k = idx >> 3;
    const int q = n1 >> 3, r = n1 & 7;
    idx = (xq < r ? xq * (q + 1) : r * (q + 1) + (xq - r) * q) + k;
  }
  const u32 en = t1[idx];
  const int z = en >> 16, mt = (en >> 8) & 255, nt = en & 255;
  const bool sh = (z == 0);
  const int e = z - 1;
  const int M = sh ? T_TOK : counts[e];
  const int lane = tid & 63, wid = tid >> 6;

  const int srow = tid >> 3, sc16 = tid & 7;
  const int scsw = (sc16 ^ (srow & 7)) * 8;
  const int* bkt = bucket + e * CAP;
  const u16* B1 = sh ? s1t : w1t + (size_t)e * INTER * DIM;
  const u16* B3 = sh ? s3t : w3t + (size_t)e * INTER * DIM;

  const u16 *aptr[4], *b1ptr[2], *b3ptr[2];
#pragma unroll
  for (int p = 0; p < 4; ++p) {
    int r = mt * BM + srow + p * 32;
    size_t arow;
    if (sh) arow = (size_t)r;
    else { int pos = r < M ? r : M - 1; arow = (size_t)(bkt[pos] >> 1); }
    aptr[p] = A + arow * DIM + scsw;
  }
#pragma unroll
  for (int p = 0; p < 2; ++p) {
    size_t nrow = (size_t)(nt * BN1 + srow + p * 32);
    b1ptr[p] = B1 + nrow * DIM + scsw;
    b3ptr[p] = B3 + nrow * DIM + scsw;
  }

  f32x4 acc1[4][2], acc3[4][2];
#pragma unroll
  for (int i = 0; i < 4; ++i)
#pragma unroll
    for (int j = 0; j < 2; ++j) {
      acc1[i][j] = f32x4{0.f, 0.f, 0.f, 0.f};
      acc3[i][j] = f32x4{0.f, 0.f, 0.f, 0.f};
    }

  const int wm = wid >> 1, wn = wid & 1;
  const int fr = lane & 15, fs = lane >> 4;
  const int csA = fr & 7;

  for (int kt = 0; kt < DIM; kt += BK) {
#pragma unroll
    for (int p = 0; p < 4; ++p)
      gload16(aptr[p] + kt, &lA[(srow + 32 * p) * BK + sc16 * 8]);
#pragma unroll
    for (int p = 0; p < 2; ++p) {
      int ldso = (srow + 32 * p) * BK + sc16 * 8;
      gload16(b1ptr[p] + kt, &lB1[ldso]);
      gload16(b3ptr[p] + kt, &lB3[ldso]);
    }
    __syncthreads();
#pragma unroll
    for (int kk = 0; kk < 2; ++kk) {
      const int c = ((kk * 4 + fs) ^ csA) * 8;
      short8 af[4];
#pragma unroll
      for (int mi = 0; mi < 4; ++mi)
        af[mi] = *reinterpret_cast<const short8*>(&lA[(wm * 64 + mi * 16 + fr) * BK + c]);
#pragma unroll
      for (int ni = 0; ni < 2; ++ni) {
        short8 b1f = *reinterpret_cast<const short8*>(&lB1[(wn * 32 + ni * 16 + fr) * BK + c]);
        short8 b3f = *reinterpret_cast<const short8*>(&lB3[(wn * 32 + ni * 16 + fr) * BK + c]);
#pragma unroll
        for (int mi = 0; mi < 4; ++mi) {
          acc1[mi][ni] = __builtin_amdgcn_mfma_f32_16x16x32_bf16(af[mi], b1f, acc1[mi][ni], 0, 0, 0);
          acc3[mi][ni] = __builtin_amdgcn_mfma_f32_16x16x32_bf16(af[mi], b3f, acc3[mi][ni], 0, 0, 0);
        }
      }
    }
    __syncthreads();
  }

  const float* bp1 = sh ? bs1 : be1 + (size_t)e * INTER;
  const float* bp3 = sh ? bs3 : be3 + (size_t)e * INTER;
#pragma unroll
  for (int mi = 0; mi < 4; ++mi) {
#pragma unroll
    for (int j = 0; j < 4; ++j) {
      int p = mt * BM + wm * 64 + mi * 16 + fs * 4 + j;
      if (p >= M) continue;
      u16* hp = sh ? hs + (size_t)p * NSH : hr + (size_t)bkt[p] * INTER;
#pragma unroll
      for (int ni = 0; ni < 2; ++ni) {
        int gcol = nt * BN1 + wn * 32 + ni * 16 + fr;
        float v1 = acc1[mi][ni][j] + bp1[gcol];
        float v3 = acc3[mi][ni][j] + bp3[gcol];
        float hv = (v1 / (1.0f + __expf(-v1))) * v3;
        hp[gcol] = f2bf(hv);
      }
    }
  }
}

// ---------------- k_g2: table-driven, flat-index XCD-swizzled; shared->out, routed->ybuf ----------------
__global__ void __launch_bounds__(256, 2) k_g2(
    const u16* __restrict__ hr, const u16* __restrict__ hs,
    const u16* __restrict__ w2t, const u16* __restrict__ s2t,
    const float* __restrict__ be2, const float* __restrict__ bs2,
    u16* __restrict__ yb, float* __restrict__ out,
    const int* __restrict__ counts, const int* __restrict__ bucket,
    const u32* __restrict__ t2) {
  // flat bijective XCD swizzle over 8*N2MAX = 896 blocks (divisible by 8)
  int lin = (int)(blockIdx.y * 8 + blockIdx.x);
  {
    const int xq = lin & 7, k = lin >> 3;
    lin = xq * (8 * N2MAX / 8) + k;       // chunk size = 112
  }
  const int by = lin >> 3, nt = lin & 7;
  if (by >= counts[18]) return;
  const u32 en = t2[by];
  const int z = en >> 8, mt = en & 255;
  const bool sh = (z == 0);
  const int e = z - 1;
  const int K = sh ? NSH : INTER;
  const int M = sh ? T_TOK : counts[e];
  const int tid = threadIdx.x;
  const int lane = tid & 63, wid = tid >> 6;

  __shared__ __align__(16) u16 lA[BM * BK];
  __shared__ __align__(16) u16 lB[BN2 * BK];

  const int srow = tid >> 3, sc16 = tid & 7;
  const int scsw = (sc16 ^ (srow & 7)) * 8;
  const int* bkt = bucket + e * CAP;
  const u16* Ab = sh ? hs : hr;
  const u16* Bb = sh ? s2t : w2t + (size_t)e * DIM * INTER;

  const u16 *aptr[4], *bptr[4];
#pragma unroll
  for (int p = 0; p < 4; ++p) {
    int r = mt * BM + srow + p * 32;
    size_t arow;
    if (sh) arow = (size_t)r;
    else { int pos = r < M ? r : M - 1; arow = (size_t)bkt[pos]; }
    aptr[p] = Ab + arow * K + scsw;
    size_t nrow = (size_t)(nt * BN2 + srow + p * 32);
    bptr[p] = Bb + nrow * K + scsw;
  }

  f32x4 acc[4][4];
#pragma unroll
  for (int i = 0; i < 4; ++i)
#pragma unroll
    for (int j = 0; j < 4; ++j) acc[i][j] = f32x4{0.f, 0.f, 0.f, 0.f};

  const int wm = wid >> 1, wn = wid & 1;
  const int fr = lane & 15, fs = lane >> 4;
  const int csA = fr & 7;

  for (int kt = 0; kt < K; kt += BK) {
#pragma unroll
    for (int p = 0; p < 4; ++p) {
      int ldso = (srow + 32 * p) * BK + sc16 * 8;
      gload16(aptr[p] + kt, &lA[ldso]);
      gload16(bptr[p] + kt, &lB[ldso]);
    }
    __syncthreads();
#pragma unroll
    for (int kk = 0; kk < 2; ++kk) {
      const int c = ((kk * 4 + fs) ^ csA) * 8;
      short8 af[4];
#pragma unroll
      for (int mi = 0; mi < 4; ++mi)
        af[mi] = *reinterpret_cast<const short8*>(&lA[(wm * 64 + mi * 16 + fr) * BK + c]);
#pragma unroll
      for (int ni = 0; ni < 4; ++ni) {
        short8 bf = *reinterpret_cast<const short8*>(&lB[(wn * 64 + ni * 16 + fr) * BK + c]);
#pragma unroll
        for (int mi = 0; mi < 4; ++mi)
          acc[mi][ni] = __builtin_amdgcn_mfma_f32_16x16x32_bf16(af[mi], bf, acc[mi][ni], 0, 0, 0);
      }
    }
    __syncthreads();
  }

  const float* bp = sh ? bs2 : be2 + (size_t)e * DIM;
#pragma unroll
  for (int mi = 0; mi < 4; ++mi) {
#pragma unroll
    for (int j = 0; j < 4; ++j) {
      int p = mt * BM + wm * 64 + mi * 16 + fs * 4 + j;
      if (p >= M) continue;
#pragma unroll
      for (int ni = 0; ni < 4; ++ni) {
        int gcol = nt * BN2 + wn * 64 + ni * 16 + fr;
        float v = acc[mi][ni][j] + bp[gcol];
        if (sh) out[(size_t)p * DIM + gcol] = v;
        else    yb[(size_t)bkt[p] * DIM + gcol] = f2bf(v);
      }
    }
  }
}

// ---------------- final combine: out += w0*y[2t] + w1*y[2t+1] (y in bf16) ----------------
__global__ void __launch_bounds__(256) k_comb(float* __restrict__ out,
                                              const u16* __restrict__ yb,
                                              const float* __restrict__ tokw) {
  const int i = blockIdx.x * 256 + threadIdx.x;   // float4 index over [T][256]
  const int t = i >> 8, c4 = i & 255;
  const float w0 = tokw[2 * t], w1 = tokw[2 * t + 1];
  const ushort4 p = *reinterpret_cast<const ushort4*>(yb + ((size_t)(2 * t) << 10) + 4 * c4);
  const ushort4 q = *reinterpret_cast<const ushort4*>(yb + ((size_t)(2 * t + 1) << 10) + 4 * c4);
  float4* o = (float4*)out + ((size_t)t << 8);
  float4 a = o[c4];
  a.x += w0 * bf2f(p.x) + w1 * bf2f(q.x);
  a.y += w0 * bf2f(p.y) + w1 * bf2f(q.y);
  a.z += w0 * bf2f(p.z) + w1 * bf2f(q.z);
  a.w += w0 * bf2f(p.w) + w1 * bf2f(q.w);
  o[c4] = a;
}

extern "C" void kernel_launch(void* const* d_in, const int* in_sizes, int n_in,
                              void* d_out, int out_size, void* d_ws, size_t ws_size,
                              hipStream_t stream) {
  const float* x   = (const float*)d_in[0];
  const float* gw  = (const float*)d_in[1];
  const float* gb  = (const float*)d_in[2];
  const float* We1 = (const float*)d_in[3];
  const float* be1 = (const float*)d_in[4];
  const float* We2 = (const float*)d_in[5];
  const float* be2 = (const float*)d_in[6];
  const float* We3 = (const float*)d_in[7];
  const float* be3 = (const float*)d_in[8];
  const float* ws1 = (const float*)d_in[9];
  const float* bs1 = (const float*)d_in[10];
  const float* ws2 = (const float*)d_in[11];
  const float* bs2 = (const float*)d_in[12];
  const float* ws3 = (const float*)d_in[13];
  const float* bs3 = (const float*)d_in[14];
  float* out = (float*)d_out;

  // workspace carve (~68 MB); ybuf (bf16, 16.8 MB) aliases w1t (dead after k_g1)
  char* w = (char*)d_ws;
  int*    counts = (int*)w;    w += 256;              // [0..15] counts, [16] spare, [17] n1, [18] n2
  u32*    t1     = (u32*)w;    w += N1MAX * 4;
  u32*    t2     = (u32*)w;    w += 512;              // N2MAX*4 = 448, rounded up
  float4* gwt4   = (float4*)w; w += (size_t)256 * NEXP * 16;   // 64KB
  int*    bucket = (int*)w;    w += (size_t)NEXP * CAP * 4;
  float*  tokw   = (float*)w;  w += (size_t)2 * T_TOK * 4;
  double* scor   = (double*)w; w += (size_t)T_TOK * NEXP * 8;
  u16*    xb     = (u16*)w;    w += (size_t)T_TOK * DIM * 2;
  char*   alias0 = w;
  u16*    w1t    = (u16*)w;    w += (size_t)NEXP * INTER * DIM * 2;
  u16*    w3t    = (u16*)w;    w += (size_t)NEXP * INTER * DIM * 2;
  u16*    w2t    = (u16*)w;    w += (size_t)NEXP * DIM * INTER * 2;
  u16*    s1t    = (u16*)w;    w += (size_t)NSH * DIM * 2;
  u16*    s3t    = (u16*)w;    w += (size_t)NSH * DIM * 2;
  u16*    s2t    = (u16*)w;    w += (size_t)DIM * NSH * 2;
  u16*    hr     = (u16*)w;    w += (size_t)2 * T_TOK * INTER * 2;
  u16*    hs     = (u16*)w;    w += (size_t)T_TOK * NSH * 2;
  u16*    ybuf   = (u16*)alias0;   // [2T][DIM] bf16 = 16.8MB, fits in w1t's slot

  // 0: gw -> gwT4 (64KB, makes score loads lane-contiguous)
  k_gwt<<<16, 256, 0, stream>>>(gw, gwt4);
  // 1: fused prep (phase-interleaved: cvt + scores + tr64 of g1-weights + zero counts)
  k_prep<<<10752, 256, 0, stream>>>(x, gwt4, xb, scor, We1, w1t, We3, w3t,
                                    ws1, s1t, ws3, s3t, counts);
  // 2: route (16 blocks) + tr64 of We2/ws2 in the otherwise-idle window (2304 blocks)
  k_route<<<16 + NTR2, 256, 0, stream>>>(scor, gb, counts, bucket, tokw,
                                         We2, w2t, ws2, s2t);
  // 3: plan (single block; counts final across kernel boundary -> race-free tables)
  k_plan<<<1, 256, 0, stream>>>(counts, t1, t2);
  // 4: GEMM1 — pure table-driven SwiGLU GEMM (sequential K, XCD-swizzled)
  k_g1<<<N1MAX, 256, 0, stream>>>(
      xb, w1t, w3t, s1t, s3t, be1, be3, bs1, bs3, hr, hs, counts, bucket, t1);
  // 5: GEMM2 (table-driven, flat-XCD-swizzled; shared -> out f32, routed -> ybuf bf16)
  k_g2<<<dim3(8, N2MAX), 256, 0, stream>>>(
      hr, hs, w2t, s2t, be2, bs2, ybuf, out, counts, bucket, t2);
  // 6: combine
  k_comb<<<(T_TOK * DIM / 4) / 256, 256, 0, stream>>>(out, ybuf, tokw);
}